// Round 3
// baseline (2751.153 us; speedup 1.0000x reference)
//
#include <hip/hip_runtime.h>
#include <hip/hip_bf16.h>
#include <cstddef>

#define NROW 4096
#define DIM  512
static const size_t NP = (size_t)NROW * NROW;   // 16777216
#define ALPHA (-8.31776616671934f)              // -log(4096), matches fp32 ref

// ---------------------------------------------------------------- sq norms
__global__ __launch_bounds__(256) void sqnorm_kernel(const float* __restrict__ x,
                                                     const float* __restrict__ y,
                                                     float* __restrict__ x2,
                                                     float* __restrict__ y2) {
    int gtid = blockIdx.x * 256 + threadIdx.x;
    int wid  = gtid >> 6;          // 8192 waves: 0..4095 -> x, 4096..8191 -> y
    int lane = gtid & 63;
    const float* src = (wid < NROW) ? x : y;
    float*       dst = (wid < NROW) ? x2 : y2;
    int row = (wid < NROW) ? wid : (wid - NROW);
    const float4* r4 = (const float4*)(src + (size_t)row * DIM);
    float4 a = r4[lane];
    float4 b = r4[lane + 64];
    float s = a.x*a.x + a.y*a.y + a.z*a.z + a.w*a.w
            + b.x*b.x + b.y*b.y + b.z*b.z + b.w*b.w;
    #pragma unroll
    for (int off = 32; off > 0; off >>= 1) s += __shfl_down(s, off);
    if (lane == 0) dst[row] = s;
}

// ---------------------------------------------------------------- S = 2 x y^T
__global__ __launch_bounds__(256) void gemm_kernel(const float* __restrict__ A,
                                                   const float* __restrict__ B,
                                                   float* __restrict__ S) {
    __shared__ float As[16][132];
    __shared__ float Bs[16][132];
    const int bm = blockIdx.y * 128, bn = blockIdx.x * 128;
    const int tid = threadIdx.x;
    const int tx = tid & 15, ty = tid >> 4;
    float acc[8][8];
    #pragma unroll
    for (int i = 0; i < 8; ++i)
        #pragma unroll
        for (int j = 0; j < 8; ++j) acc[i][j] = 0.f;

    for (int kt = 0; kt < DIM; kt += 16) {
        #pragma unroll
        for (int h = 0; h < 2; ++h) {
            int f = tid + h * 256;          // float4 id within the 128x16 tile
            int row = f >> 2, kk = (f & 3) << 2;
            float4 a4 = *(const float4*)(A + (size_t)(bm + row) * DIM + kt + kk);
            As[kk+0][row] = a4.x; As[kk+1][row] = a4.y;
            As[kk+2][row] = a4.z; As[kk+3][row] = a4.w;
            float4 b4 = *(const float4*)(B + (size_t)(bn + row) * DIM + kt + kk);
            Bs[kk+0][row] = b4.x; Bs[kk+1][row] = b4.y;
            Bs[kk+2][row] = b4.z; Bs[kk+3][row] = b4.w;
        }
        __syncthreads();
        #pragma unroll
        for (int k = 0; k < 16; ++k) {
            float ar[8], br[8];
            #pragma unroll
            for (int i = 0; i < 8; ++i) ar[i] = As[k][ty*8 + i];
            #pragma unroll
            for (int j = 0; j < 8; ++j) br[j] = Bs[k][tx*8 + j];
            #pragma unroll
            for (int i = 0; i < 8; ++i)
                #pragma unroll
                for (int j = 0; j < 8; ++j)
                    acc[i][j] = __fmaf_rn(ar[i], br[j], acc[i][j]);
        }
        __syncthreads();
    }
    // scalar stores: S base is only 4B-aligned (lives inside d_out at +1 offset)
    #pragma unroll
    for (int i = 0; i < 8; ++i) {
        size_t off = (size_t)(bm + ty*8 + i) * NROW + bn + tx*8;
        #pragma unroll
        for (int j = 0; j < 8; ++j) S[off + j] = 2.0f * acc[i][j];
    }
}

// ---------------------------------------------------------------- transpose
__global__ __launch_bounds__(256) void transpose_kernel(const float* __restrict__ in,
                                                        float* __restrict__ out) {
    __shared__ float tile[64][65];
    int bx = blockIdx.x * 64, by = blockIdx.y * 64;
    int tx = threadIdx.x & 63, tw = threadIdx.x >> 6;
    #pragma unroll
    for (int r = tw; r < 64; r += 4)
        tile[r][tx] = in[(size_t)(by + r) * NROW + bx + tx];
    __syncthreads();
    #pragma unroll
    for (int r = tw; r < 64; r += 4)
        out[(size_t)(bx + r) * NROW + by + tx] = tile[tx][r];
}

// ---------------------------------------------------------------- init
__global__ void init_kernel(const float* __restrict__ y2,
                            float* __restrict__ gt,
                            float* __restrict__ cost) {
    int i = blockIdx.x * 256 + threadIdx.x;
    if (i < NROW) gt[i] = -y2[i];
    if (i == 0) cost[0] = 0.f;
}

// ---------------------------------------------------------------- lse pass
// out[row] = ALPHA - logsumexp_j( u[j] + M[row][j] ),  one block per row
__global__ __launch_bounds__(256) void lse_pass_kernel(const float* __restrict__ M,
                                                       const float* __restrict__ u,
                                                       float* __restrict__ outv) {
    const int row = blockIdx.x;
    const float* mrow = M + (size_t)row * NROW;
    const int t = threadIdx.x;
    float m = -3.0e38f, s = 0.f;
    #pragma unroll
    for (int h = 0; h < 16; ++h) {
        int j = t + h * 256;                       // coalesced dword stream
        float v = u[j] + mrow[j];
        float d = v - m;
        float e = __expf(-fabsf(d));               // exactly one exp/element
        s = (d > 0.f) ? __fmaf_rn(s, e, 1.0f) : (s + e);
        m = fmaxf(m, v);
    }
    // wave butterfly merge of (m, s)
    #pragma unroll
    for (int off = 1; off < 64; off <<= 1) {
        float m2 = __shfl_xor(m, off);
        float s2 = __shfl_xor(s, off);
        float d = m - m2;
        float e = __expf(-fabsf(d));
        s = (d > 0.f) ? __fmaf_rn(s2, e, s) : __fmaf_rn(s, e, s2);
        m = fmaxf(m, m2);
    }
    __shared__ float sm[4], ss[4];
    int lane = t & 63, w = t >> 6;
    if (lane == 0) { sm[w] = m; ss[w] = s; }
    __syncthreads();
    if (t == 0) {
        float M0 = sm[0], S0 = ss[0];
        #pragma unroll
        for (int w2 = 1; w2 < 4; ++w2) {
            float m2 = sm[w2], s2 = ss[w2];
            float d = M0 - m2;
            float e = __expf(-fabsf(d));
            S0 = (d > 0.f) ? __fmaf_rn(s2, e, S0) : __fmaf_rn(S0, e, s2);
            M0 = fmaxf(M0, m2);
        }
        outv[row] = ALPHA - (M0 + __logf(S0));
    }
}

// ---------------------------------------------------------------- finalize
// pi = exp(ft_i + gt_j + S_ij); C = max(x2_i + y2_j - S_ij, 0); cost += pi*C
__global__ __launch_bounds__(256) void finalize_kernel(const float* __restrict__ S,
                                                       const float* __restrict__ ft,
                                                       const float* __restrict__ gt,
                                                       const float* __restrict__ x2,
                                                       const float* __restrict__ y2,
                                                       float* __restrict__ pi,
                                                       float* __restrict__ C,
                                                       float* __restrict__ cost) {
    const int row = blockIdx.x;
    const size_t base = (size_t)row * NROW;
    const float fi  = ft[row];
    const float x2i = x2[row];
    float acc = 0.f;
    #pragma unroll
    for (int h = 0; h < 16; ++h) {
        int j = threadIdx.x + h * 256;
        float sv = S[base + j];                    // read BEFORE in-place C write
        float p  = __expf(fi + gt[j] + sv);
        float c  = fmaxf(x2i + y2[j] - sv, 0.f);
        pi[base + j] = p;
        C[base + j]  = c;
        acc = __fmaf_rn(p, c, acc);
    }
    #pragma unroll
    for (int off = 32; off > 0; off >>= 1) acc += __shfl_down(acc, off);
    __shared__ float sa[4];
    int lane = threadIdx.x & 63, w = threadIdx.x >> 6;
    if (lane == 0) sa[w] = acc;
    __syncthreads();
    if (threadIdx.x == 0)
        atomicAdd(cost, sa[0] + sa[1] + sa[2] + sa[3]);
}

// ---------------------------------------------------------------- launch
extern "C" void kernel_launch(void* const* d_in, const int* in_sizes, int n_in,
                              void* d_out, int out_size, void* d_ws, size_t ws_size,
                              hipStream_t stream) {
    const float* x = (const float*)d_in[0];
    const float* y = (const float*)d_in[1];
    float* out  = (float*)d_out;
    float* cost = out;                 // [1]
    float* pi   = out + 1;             // [16.7M]  (used as S^T scratch during iters)
    float* Cpt  = out + 1 + NP;        // [16.7M]  (used as S scratch during iters)
    float* S  = Cpt;
    float* ST = pi;

    float* ws = (float*)d_ws;          // 64 KB of small vectors
    float* x2 = ws;
    float* y2 = ws + NROW;
    float* ft = ws + 2 * NROW;
    float* gt = ws + 3 * NROW;

    sqnorm_kernel<<<2048, 256, 0, stream>>>(x, y, x2, y2);
    gemm_kernel<<<dim3(32, 32), 256, 0, stream>>>(x, y, S);
    transpose_kernel<<<dim3(64, 64), 256, 0, stream>>>(S, ST);
    init_kernel<<<16, 256, 0, stream>>>(y2, gt, cost);

    for (int it = 0; it < 100; ++it) {
        lse_pass_kernel<<<NROW, 256, 0, stream>>>(S,  gt, ft);   // f update
        lse_pass_kernel<<<NROW, 256, 0, stream>>>(ST, ft, gt);   // g update
    }

    finalize_kernel<<<NROW, 256, 0, stream>>>(S, ft, gt, x2, y2, pi, Cpt, cost);
}